// Round 11
// baseline (580.547 us; speedup 1.0000x reference)
//
#include <hip/hip_runtime.h>

typedef unsigned short u16;
typedef __attribute__((ext_vector_type(8))) __bf16 bf16x8;
typedef __attribute__((ext_vector_type(4))) float f32x4;
typedef __attribute__((ext_vector_type(16))) float f32x16;
typedef __attribute__((ext_vector_type(4))) u16 u16x4;
typedef __attribute__((ext_vector_type(8))) u16 u16x8;

#define DEVI static __device__ __forceinline__

DEVI u16 f2bf(float f) {
    unsigned u = __float_as_uint(f);
    u += 0x7fffu + ((u >> 16) & 1u);   // RNE
    return (u16)(u >> 16);
}
DEVI float bf2f(u16 b) { return __uint_as_float(((unsigned)b) << 16); }

// fast GELU: Abramowitz-Stegun 7.1.26 erf approx, |err| < 1.5e-7
DEVI float gelu_f(float v) {
    float z = fabsf(v) * 0.70710678118654752f;
    float t = 1.f / (1.f + 0.3275911f * z);
    float p = t * (0.254829592f + t * (-0.284496736f + t * (1.421413741f +
              t * (-1.453152027f + t * 1.061405429f))));
    float erfz = 1.f - p * __expf(-z * z);
    erfz = (v < 0.f) ? -erfz : erfz;
    return 0.5f * v * (1.f + erfz);
}

// async global->LDS, 16B per lane. LDS dest is wave-uniform base + lane*16.
DEVI void gll16(const void* g, void* s) {
    __builtin_amdgcn_global_load_lds((__attribute__((address_space(1))) void*)(g),
                                     (__attribute__((address_space(3))) void*)(s),
                                     16, 0, 0);
}

// ---------------------------------------------------------------------------
// Weight convert+transpose: in f32 [K][N] -> out bf16 [N][K]
// ---------------------------------------------------------------------------
__global__ __launch_bounds__(256) void wtrans(const float* __restrict__ in,
                                              u16* __restrict__ out, int K, int N) {
    __shared__ float tile[32][33];
    int t = threadIdx.x;
    int n0 = blockIdx.x * 32, k0 = blockIdx.y * 32;
    int r = t >> 3, c4 = (t & 7) << 2;
    float4 v = *(const float4*)(in + (size_t)(k0 + r) * N + n0 + c4);
    tile[r][c4 + 0] = v.x; tile[r][c4 + 1] = v.y;
    tile[r][c4 + 2] = v.z; tile[r][c4 + 3] = v.w;
    __syncthreads();
    u16x4 o;
    o.x = f2bf(tile[c4 + 0][r]);
    o.y = f2bf(tile[c4 + 1][r]);
    o.z = f2bf(tile[c4 + 2][r]);
    o.w = f2bf(tile[c4 + 3][r]);
    *(u16x4*)(out + (size_t)(n0 + r) * K + k0 + c4) = o;
}

// ---------------------------------------------------------------------------
// LayerNorm: f32 [M][768] -> bf16 [M][768]; one wave per row.
// ---------------------------------------------------------------------------
__global__ __launch_bounds__(256) void ln_bf16(const float* __restrict__ x,
                                               const float* __restrict__ g,
                                               const float* __restrict__ b,
                                               u16* __restrict__ out) {
    int l = threadIdx.x & 63;
    size_t row = (size_t)blockIdx.x * 4 + (threadIdx.x >> 6);
    const float4* xr = (const float4*)(x + row * 768);
    float4 vv[3];
    vv[0] = xr[l]; vv[1] = xr[l + 64]; vv[2] = xr[l + 128];
    float s = 0.f, ss = 0.f;
#pragma unroll
    for (int i = 0; i < 3; ++i) {
        s  += vv[i].x + vv[i].y + vv[i].z + vv[i].w;
        ss += vv[i].x * vv[i].x + vv[i].y * vv[i].y + vv[i].z * vv[i].z + vv[i].w * vv[i].w;
    }
#pragma unroll
    for (int m = 1; m < 64; m <<= 1) { s += __shfl_xor(s, m); ss += __shfl_xor(ss, m); }
    float mean = s * (1.f / 768.f);
    float rstd = rsqrtf(ss * (1.f / 768.f) - mean * mean + 1e-5f);
    const float4* gr = (const float4*)g;
    const float4* br = (const float4*)b;
    u16* orow = out + row * 768;
#pragma unroll
    for (int i = 0; i < 3; ++i) {
        float4 gv = gr[l + i * 64], bv = br[l + i * 64];
        u16x4 o;
        o.x = f2bf((vv[i].x - mean) * rstd * gv.x + bv.x);
        o.y = f2bf((vv[i].y - mean) * rstd * gv.y + bv.y);
        o.z = f2bf((vv[i].z - mean) * rstd * gv.z + bv.z);
        o.w = f2bf((vv[i].w - mean) * rstd * gv.w + bv.w);
        *(u16x4*)(orow + l * 4 + i * 256) = o;
    }
}

// ---------------------------------------------------------------------------
// GEMM 128x128 — R10 base (R1 loop + XCD swizzle + XOR bank-swizzle + fast
// epilogue) with R11 change: mfma_f32_32x32x16_bf16 (16 MFMA/tile/wave vs 32,
// same 16 ds_read) to cut issue-port pressure (fc1 was MfmaUtil32+VALU61=93%).
// A/B frag: lane l = row l&31, k-chunk l>>5; LDS chunk (s*2+lhi)^(l&7) -- same
// involution as staging pre-swizzle. C/D: col=lane&31,
// row=(reg&3)+8*(reg>>2)+4*(lane>>5)  [m74/m101 verified mapping].
// C[M][N] = A[M][K] (bf16) @ BT[N][K] (bf16). 4 waves (2x2), 64x64/wave.
// ---------------------------------------------------------------------------
#define MFMA32(a, b, c) __builtin_amdgcn_mfma_f32_32x32x16_bf16(a, b, c, 0, 0, 0)

template <int HAS_BIAS, int HAS_RES, int DO_GELU, int OUT_BF16>
__global__ __launch_bounds__(256, 2) void gemm128(const u16* __restrict__ A,
                                                  const u16* __restrict__ BT,
                                                  const float* __restrict__ bias,
                                                  const float* res, void* outp,
                                                  int M, int N, int K, int nbx) {
    __shared__ __attribute__((aligned(16))) u16 lds_a[128 * 64];
    __shared__ __attribute__((aligned(16))) u16 lds_b[128 * 64];
    const int tid = threadIdx.x, l = tid & 63, wid = tid >> 6;
    const int l31 = l & 31, lhi = l >> 5;
    const int wr = wid >> 1, wcn = wid & 1;
    const int xr7 = l & 7;
    // chunked XCD swizzle: consecutive work items (sharing A panel) -> same XCD
    const int nwg = gridDim.x, orig = blockIdx.x;
    const int swz = (orig & 7) * (nwg >> 3) + (orig >> 3);
    const int bx = swz % nbx, by = swz / nbx;
    const int m0 = by * 128, n0 = bx * 128;
    const int nkt = K >> 6;

    const int arow = wr * 64 + l31;
    const int brow = wcn * 64 + l31;

    f32x16 acc[2][2];
#pragma unroll
    for (int mt = 0; mt < 2; ++mt)
#pragma unroll
        for (int nt = 0; nt < 2; ++nt)
#pragma unroll
            for (int r = 0; r < 16; ++r) acc[mt][nt][r] = 0.f;

    for (int kt = 0; kt < nkt; ++kt) {
#pragma unroll
        for (int it = 0; it < 4; ++it) {
            int ci = it * 256 + tid;          // 16B chunk index, 0..1023
            int rowa = ci >> 3, sl = ci & 7;  // 8 chunks per 64-elem row
            int slx = sl ^ (rowa & 7);        // pre-swizzled global chunk
            gll16(A  + (size_t)(m0 + rowa) * K + kt * 64 + slx * 8, lds_a + ci * 8);
            gll16(BT + (size_t)(n0 + rowa) * K + kt * 64 + slx * 8, lds_b + ci * 8);
        }
        __syncthreads();
#pragma unroll
        for (int s = 0; s < 4; ++s) {         // 4 k-steps of 16
            const int ch = ((s * 2 + lhi) ^ xr7) * 8;
            bf16x8 a0 = *(const bf16x8*)&lds_a[arow * 64 + ch];
            bf16x8 a1 = *(const bf16x8*)&lds_a[(arow + 32) * 64 + ch];
            bf16x8 b0 = *(const bf16x8*)&lds_b[brow * 64 + ch];
            bf16x8 b1 = *(const bf16x8*)&lds_b[(brow + 32) * 64 + ch];
            acc[0][0] = MFMA32(a0, b0, acc[0][0]);
            acc[0][1] = MFMA32(a0, b1, acc[0][1]);
            acc[1][0] = MFMA32(a1, b0, acc[1][0]);
            acc[1][1] = MFMA32(a1, b1, acc[1][1]);
        }
        __syncthreads();
    }

    // ---- epilogue: per-32x32-subtile LDS transpose -> coalesced stores ----
    // scratch per wave: 32 rows x 36 floats = 4608 B; 4 waves = 18.4 KB
    float* sc = (float*)&lds_a[0] + (size_t)wid * 1152;
#pragma unroll
    for (int mt = 0; mt < 2; ++mt)
#pragma unroll
        for (int nt = 0; nt < 2; ++nt) {
            const float bsv = HAS_BIAS ? bias[n0 + wcn * 64 + nt * 32 + l31] : 0.f;
#pragma unroll
            for (int r = 0; r < 16; ++r) {
                const int row = (r & 3) + 8 * (r >> 2) + 4 * lhi;
                float v = acc[mt][nt][r] + bsv;
                if (DO_GELU) v = gelu_f(v);
                sc[row * 36 + l31] = v;
            }
            const int rowbase = m0 + wr * 64 + mt * 32;
            const int colbase = n0 + wcn * 64 + nt * 32;
#pragma unroll
            for (int p = 0; p < 2; ++p) {
                const int rr = p * 16 + (l >> 2);
                const int cc = (l & 3) * 8;
                float4 f0 = *(float4*)&sc[rr * 36 + cc];
                float4 f1 = *(float4*)&sc[rr * 36 + cc + 4];
                const size_t idx = (size_t)(rowbase + rr) * N + colbase + cc;
                if (OUT_BF16) {
                    u16x8 ov;
                    ov[0] = f2bf(f0.x); ov[1] = f2bf(f0.y);
                    ov[2] = f2bf(f0.z); ov[3] = f2bf(f0.w);
                    ov[4] = f2bf(f1.x); ov[5] = f2bf(f1.y);
                    ov[6] = f2bf(f1.z); ov[7] = f2bf(f1.w);
                    *(u16x8*)((u16*)outp + idx) = ov;
                } else {
                    if (HAS_RES) {
                        float4 r0 = *(const float4*)(res + idx);
                        float4 r1 = *(const float4*)(res + idx + 4);
                        f0.x += r0.x; f0.y += r0.y; f0.z += r0.z; f0.w += r0.w;
                        f1.x += r1.x; f1.y += r1.y; f1.z += r1.z; f1.w += r1.w;
                    }
                    *(float4*)((float*)outp + idx) = f0;
                    *(float4*)((float*)outp + idx + 4) = f1;
                }
            }
        }
}

// ---------------------------------------------------------------------------
// Spatial attention: one block per (b,t,h). qkv bf16 [16384][2304],
// q|k|v at col 0|768|1536 (+h*64). N=256 keys, D=64. Out bf16 [16384][768].
// ---------------------------------------------------------------------------
__global__ __launch_bounds__(256, 2) void sattn(const u16* __restrict__ qkv,
                                                u16* __restrict__ attno) {
    __shared__ __attribute__((aligned(16))) u16 p_lds[4][16][264];
    __shared__ __attribute__((aligned(16))) u16 vt_lds[64][264];
    const int tid = threadIdx.x, l = tid & 63, w = tid >> 6;
    const int lr = l & 15, lg = l >> 4;
    const int bid = blockIdx.x;
    const int h = bid % 12;
    const size_t R0 = (size_t)(bid / 12) * 256;
    const u16* base = qkv + R0 * 2304;
    const f32x4 FZ = {0.f, 0.f, 0.f, 0.f};

    {
        const u16* vrow = base + (size_t)tid * 2304 + 1536 + h * 64;
#pragma unroll
        for (int c = 0; c < 8; ++c) {
            bf16x8 vv = *(const bf16x8*)(vrow + c * 8);
            const u16* pv = (const u16*)&vv;
#pragma unroll
            for (int e = 0; e < 8; ++e) vt_lds[c * 8 + e][tid] = pv[e];
        }
    }
    __syncthreads();

    u16* attbase = attno + R0 * 768 + h * 64;
    for (int qb = 0; qb < 4; ++qb) {
        const int qrow0 = qb * 64 + w * 16;
        f32x4 acc[16];
#pragma unroll
        for (int nt = 0; nt < 16; ++nt) acc[nt] = FZ;
        const u16* qp = base + (size_t)(qrow0 + lr) * 2304 + h * 64;
#pragma unroll
        for (int ks = 0; ks < 2; ++ks) {
            bf16x8 af = *(const bf16x8*)(qp + ks * 32 + lg * 8);
#pragma unroll
            for (int nt = 0; nt < 16; ++nt) {
                const u16* kp = base + (size_t)(nt * 16 + lr) * 2304 + 768 + h * 64 + ks * 32 + lg * 8;
                bf16x8 bfr = *(const bf16x8*)kp;
                acc[nt] = __builtin_amdgcn_mfma_f32_16x16x32_bf16(af, bfr, acc[nt], 0, 0, 0);
            }
        }
#pragma unroll
        for (int r = 0; r < 4; ++r) {
            float m = acc[0][r] * 0.125f;
#pragma unroll
            for (int nt = 0; nt < 16; ++nt) { acc[nt][r] *= 0.125f; m = fmaxf(m, acc[nt][r]); }
            m = fmaxf(m, __shfl_xor(m, 1));
            m = fmaxf(m, __shfl_xor(m, 2));
            m = fmaxf(m, __shfl_xor(m, 4));
            m = fmaxf(m, __shfl_xor(m, 8));
            float ssum = 0.f;
#pragma unroll
            for (int nt = 0; nt < 16; ++nt) {
                float e = __expf(acc[nt][r] - m);
                acc[nt][r] = e; ssum += e;
            }
            ssum += __shfl_xor(ssum, 1);
            ssum += __shfl_xor(ssum, 2);
            ssum += __shfl_xor(ssum, 4);
            ssum += __shfl_xor(ssum, 8);
            float inv = 1.f / ssum;
#pragma unroll
            for (int nt = 0; nt < 16; ++nt) acc[nt][r] *= inv;
        }
#pragma unroll
        for (int nt = 0; nt < 16; ++nt)
#pragma unroll
            for (int r = 0; r < 4; ++r)
                p_lds[w][lg * 4 + r][nt * 16 + lr] = f2bf(acc[nt][r]);
        __syncthreads();
        f32x4 oacc[4];
#pragma unroll
        for (int dt = 0; dt < 4; ++dt) oacc[dt] = FZ;
#pragma unroll
        for (int ks = 0; ks < 8; ++ks) {
            bf16x8 af = *(const bf16x8*)&p_lds[w][lr][ks * 32 + lg * 8];
#pragma unroll
            for (int dt = 0; dt < 4; ++dt) {
                bf16x8 bfr = *(const bf16x8*)&vt_lds[dt * 16 + lr][ks * 32 + lg * 8];
                oacc[dt] = __builtin_amdgcn_mfma_f32_16x16x32_bf16(af, bfr, oacc[dt], 0, 0, 0);
            }
        }
#pragma unroll
        for (int dt = 0; dt < 4; ++dt)
#pragma unroll
            for (int r = 0; r < 4; ++r)
                attbase[(size_t)(qrow0 + lg * 4 + r) * 768 + dt * 16 + lr] = f2bf(oacc[dt][r]);
        __syncthreads();
    }
}

// ---------------------------------------------------------------------------
// Temporal attention (causal, T=16): one wave per (b,n,h). Vector math.
// ---------------------------------------------------------------------------
__global__ __launch_bounds__(256, 4) void tattn(const u16* __restrict__ qkv,
                                                u16* __restrict__ attno) {
    __shared__ float p_lds[4][16][17];
    const int tid = threadIdx.x, l = tid & 63, wv = tid >> 6;
    const int gw = blockIdx.x * 4 + wv;
    const int h = gw % 12;
    const int bn = gw / 12;
    const int n = bn & 255, b = bn >> 8;
    const u16* base = qkv + ((size_t)(b * 16) * 256 + n) * 2304;
    const size_t tstr = (size_t)256 * 2304;
    const int tk = l & 15, g = l >> 4;

    bf16x8 kv[8];
    const u16* kp = base + (size_t)tk * tstr + 768 + h * 64;
#pragma unroll
    for (int c = 0; c < 8; ++c) kv[c] = *(const bf16x8*)(kp + c * 8);

#pragma unroll
    for (int pass = 0; pass < 4; ++pass) {
        int tq = pass * 4 + g;
        const u16* qp = base + (size_t)tq * tstr + h * 64;
        float s = 0.f;
#pragma unroll
        for (int c = 0; c < 8; ++c) {
            bf16x8 qv = *(const bf16x8*)(qp + c * 8);
#pragma unroll
            for (int e = 0; e < 8; ++e) s += (float)qv[e] * (float)kv[c][e];
        }
        s = (tk <= tq) ? s * 0.125f : -1e30f;
        float m = s;
        m = fmaxf(m, __shfl_xor(m, 1));
        m = fmaxf(m, __shfl_xor(m, 2));
        m = fmaxf(m, __shfl_xor(m, 4));
        m = fmaxf(m, __shfl_xor(m, 8));
        float p = __expf(s - m);
        float ssum = p;
        ssum += __shfl_xor(ssum, 1);
        ssum += __shfl_xor(ssum, 2);
        ssum += __shfl_xor(ssum, 4);
        ssum += __shfl_xor(ssum, 8);
        p_lds[wv][tq][tk] = p / ssum;
    }
    __syncthreads();
    float vreg[16];
#pragma unroll
    for (int t2 = 0; t2 < 16; ++t2)
        vreg[t2] = bf2f(base[(size_t)t2 * tstr + 1536 + h * 64 + l]);
    u16* ob = attno + ((size_t)(b * 16) * 256 + n) * 768 + h * 64 + l;
#pragma unroll
    for (int tq = 0; tq < 16; ++tq) {
        float o = 0.f;
#pragma unroll
        for (int t2 = 0; t2 < 16; ++t2) o += p_lds[wv][tq][t2] * vreg[t2];
        ob[(size_t)tq * 256 * 768] = f2bf(o);
    }
}

// ---------------------------------------------------------------------------
extern "C" void kernel_launch(void* const* d_in, const int* in_sizes, int n_in,
                              void* d_out, int out_size, void* d_ws, size_t ws_size,
                              hipStream_t stream) {
    (void)in_sizes; (void)n_in; (void)out_size; (void)ws_size;
    const float* x       = (const float*)d_in[0];
    const float* ln1s_g  = (const float*)d_in[1];
    const float* ln1s_b  = (const float*)d_in[2];
    const float* ln1t_g  = (const float*)d_in[3];
    const float* ln1t_b  = (const float*)d_in[4];
    const float* ln2_g   = (const float*)d_in[5];
    const float* ln2_b   = (const float*)d_in[6];
    const float* Wqkv_s  = (const float*)d_in[7];
    const float* Wproj_s = (const float*)d_in[8];
    const float* bproj_s = (const float*)d_in[9];
    const float* Wqkv_t  = (const float*)d_in[10];
    const float* Wproj_t = (const float*)d_in[11];
    const float* bproj_t = (const float*)d_in[12];
    const float* Wfc1    = (const float*)d_in[13];
    const float* bfc1    = (const float*)d_in[14];
    const float* Wfc2    = (const float*)d_in[15];
    const float* bfc2    = (const float*)d_in[16];
    float* out = (float*)d_out;

    const int M = 16384, C = 768, HID = 3072, NQKV = 2304;

    char* p = (char*)d_ws;
    auto carve = [&](size_t bytes) {
        char* r = p;
        p += (bytes + 255) & ~(size_t)255;
        return r;
    };
    u16* wqkvT_s  = (u16*)carve((size_t)NQKV * C * 2);
    u16* wprojT_s = (u16*)carve((size_t)C * C * 2);
    u16* wqkvT_t  = (u16*)carve((size_t)NQKV * C * 2);
    u16* wprojT_t = (u16*)carve((size_t)C * C * 2);
    u16* wfc1T    = (u16*)carve((size_t)HID * C * 2);
    u16* wfc2T    = (u16*)carve((size_t)C * HID * 2);
    u16* xn       = (u16*)carve((size_t)M * C * 2);
    u16* attno    = (u16*)carve((size_t)M * C * 2);
    u16* big      = (u16*)carve((size_t)M * HID * 2);  // qkv (M x 2304) or h1 (M x 3072)

    // weight transposes (f32 [K][N] -> bf16 [N][K])
    wtrans<<<dim3(NQKV / 32, C / 32), 256, 0, stream>>>(Wqkv_s, wqkvT_s, C, NQKV);
    wtrans<<<dim3(C / 32, C / 32), 256, 0, stream>>>(Wproj_s, wprojT_s, C, C);
    wtrans<<<dim3(NQKV / 32, C / 32), 256, 0, stream>>>(Wqkv_t, wqkvT_t, C, NQKV);
    wtrans<<<dim3(C / 32, C / 32), 256, 0, stream>>>(Wproj_t, wprojT_t, C, C);
    wtrans<<<dim3(HID / 32, C / 32), 256, 0, stream>>>(Wfc1, wfc1T, C, HID);
    wtrans<<<dim3(C / 32, HID / 32), 256, 0, stream>>>(Wfc2, wfc2T, HID, C);

    // ---- spatial attention block ----
    ln_bf16<<<M / 4, 256, 0, stream>>>(x, ln1s_g, ln1s_b, xn);
    gemm128<0, 0, 0, 1><<<(NQKV / 128) * (M / 128), 256, 0, stream>>>(
        xn, wqkvT_s, nullptr, nullptr, big, M, NQKV, C, NQKV / 128);
    sattn<<<768, 256, 0, stream>>>(big, attno);
    gemm128<1, 1, 0, 0><<<(C / 128) * (M / 128), 256, 0, stream>>>(
        attno, wprojT_s, bproj_s, x, out, M, C, C, C / 128);

    // ---- temporal attention block ----
    ln_bf16<<<M / 4, 256, 0, stream>>>(out, ln1t_g, ln1t_b, xn);
    gemm128<0, 0, 0, 1><<<(NQKV / 128) * (M / 128), 256, 0, stream>>>(
        xn, wqkvT_t, nullptr, nullptr, big, M, NQKV, C, NQKV / 128);
    tattn<<<12288 / 4, 256, 0, stream>>>(big, attno);
    gemm128<1, 1, 0, 0><<<(C / 128) * (M / 128), 256, 0, stream>>>(
        attno, wprojT_t, bproj_t, out, out, M, C, C, C / 128);

    // ---- MLP block ----
    ln_bf16<<<M / 4, 256, 0, stream>>>(out, ln2_g, ln2_b, xn);
    gemm128<1, 0, 1, 1><<<(HID / 128) * (M / 128), 256, 0, stream>>>(
        xn, wfc1T, bfc1, nullptr, big, M, HID, C, HID / 128);
    gemm128<1, 1, 0, 0><<<(C / 128) * (M / 128), 256, 0, stream>>>(
        big, wfc2T, bfc2, out, out, M, C, HID, C / 128);
}

// Round 12
// 543.189 us; speedup vs baseline: 1.0688x; 1.0688x over previous
//
#include <hip/hip_runtime.h>

typedef unsigned short u16;
typedef __attribute__((ext_vector_type(8))) __bf16 bf16x8;
typedef __attribute__((ext_vector_type(4))) float f32x4;
typedef __attribute__((ext_vector_type(4))) u16 u16x4;
typedef __attribute__((ext_vector_type(8))) u16 u16x8;

#define DEVI static __device__ __forceinline__

DEVI u16 f2bf(float f) {
    unsigned u = __float_as_uint(f);
    u += 0x7fffu + ((u >> 16) & 1u);   // RNE
    return (u16)(u >> 16);
}
DEVI float bf2f(u16 b) { return __uint_as_float(((unsigned)b) << 16); }

// fast GELU: Abramowitz-Stegun 7.1.26 erf approx, |err| < 1.5e-7
DEVI float gelu_f(float v) {
    float z = fabsf(v) * 0.70710678118654752f;
    float t = 1.f / (1.f + 0.3275911f * z);
    float p = t * (0.254829592f + t * (-0.284496736f + t * (1.421413741f +
              t * (-1.453152027f + t * 1.061405429f))));
    float erfz = 1.f - p * __expf(-z * z);
    erfz = (v < 0.f) ? -erfz : erfz;
    return 0.5f * v * (1.f + erfz);
}

// async global->LDS, 16B per lane. LDS dest is wave-uniform base + lane*16.
DEVI void gll16(const void* g, void* s) {
    __builtin_amdgcn_global_load_lds((__attribute__((address_space(1))) void*)(g),
                                     (__attribute__((address_space(3))) void*)(s),
                                     16, 0, 0);
}

// ---------------------------------------------------------------------------
// Weight convert+transpose: in f32 [K][N] -> out bf16 [N][K]
// ---------------------------------------------------------------------------
__global__ __launch_bounds__(256) void wtrans(const float* __restrict__ in,
                                              u16* __restrict__ out, int K, int N) {
    __shared__ float tile[32][33];
    int t = threadIdx.x;
    int n0 = blockIdx.x * 32, k0 = blockIdx.y * 32;
    int r = t >> 3, c4 = (t & 7) << 2;
    float4 v = *(const float4*)(in + (size_t)(k0 + r) * N + n0 + c4);
    tile[r][c4 + 0] = v.x; tile[r][c4 + 1] = v.y;
    tile[r][c4 + 2] = v.z; tile[r][c4 + 3] = v.w;
    __syncthreads();
    u16x4 o;
    o.x = f2bf(tile[c4 + 0][r]);
    o.y = f2bf(tile[c4 + 1][r]);
    o.z = f2bf(tile[c4 + 2][r]);
    o.w = f2bf(tile[c4 + 3][r]);
    *(u16x4*)(out + (size_t)(n0 + r) * K + k0 + c4) = o;
}

// ---------------------------------------------------------------------------
// LayerNorm: f32 [M][768] -> bf16 [M][768]; one wave per row.
// ---------------------------------------------------------------------------
__global__ __launch_bounds__(256) void ln_bf16(const float* __restrict__ x,
                                               const float* __restrict__ g,
                                               const float* __restrict__ b,
                                               u16* __restrict__ out) {
    int l = threadIdx.x & 63;
    size_t row = (size_t)blockIdx.x * 4 + (threadIdx.x >> 6);
    const float4* xr = (const float4*)(x + row * 768);
    float4 vv[3];
    vv[0] = xr[l]; vv[1] = xr[l + 64]; vv[2] = xr[l + 128];
    float s = 0.f, ss = 0.f;
#pragma unroll
    for (int i = 0; i < 3; ++i) {
        s  += vv[i].x + vv[i].y + vv[i].z + vv[i].w;
        ss += vv[i].x * vv[i].x + vv[i].y * vv[i].y + vv[i].z * vv[i].z + vv[i].w * vv[i].w;
    }
#pragma unroll
    for (int m = 1; m < 64; m <<= 1) { s += __shfl_xor(s, m); ss += __shfl_xor(ss, m); }
    float mean = s * (1.f / 768.f);
    float rstd = rsqrtf(ss * (1.f / 768.f) - mean * mean + 1e-5f);
    const float4* gr = (const float4*)g;
    const float4* br = (const float4*)b;
    u16* orow = out + row * 768;
#pragma unroll
    for (int i = 0; i < 3; ++i) {
        float4 gv = gr[l + i * 64], bv = br[l + i * 64];
        u16x4 o;
        o.x = f2bf((vv[i].x - mean) * rstd * gv.x + bv.x);
        o.y = f2bf((vv[i].y - mean) * rstd * gv.y + bv.y);
        o.z = f2bf((vv[i].z - mean) * rstd * gv.z + bv.z);
        o.w = f2bf((vv[i].w - mean) * rstd * gv.w + bv.w);
        *(u16x4*)(orow + l * 4 + i * 256) = o;
    }
}

// ---------------------------------------------------------------------------
// GEMM 128x128 — R10 (verbatim): R1 loop + chunked XCD swizzle + XOR
// bank-swizzle both sides + coalesced LDS-transpose epilogue + fast GELU.
// C[M][N] = A[M][K] (bf16) @ BT[N][K] (bf16). 4 waves (2x2), 64x64/wave.
// ---------------------------------------------------------------------------
#define MFMA_(a, b, c) __builtin_amdgcn_mfma_f32_16x16x32_bf16(a, b, c, 0, 0, 0)

template <int HAS_BIAS, int HAS_RES, int DO_GELU, int OUT_BF16>
__global__ __launch_bounds__(256, 2) void gemm128(const u16* __restrict__ A,
                                                  const u16* __restrict__ BT,
                                                  const float* __restrict__ bias,
                                                  const float* res, void* outp,
                                                  int M, int N, int K, int nbx) {
    __shared__ __attribute__((aligned(16))) u16 lds_a[128 * 64];
    __shared__ __attribute__((aligned(16))) u16 lds_b[128 * 64];
    const int tid = threadIdx.x, l = tid & 63, wid = tid >> 6;
    const int l15 = l & 15, lhi = l >> 4;
    const int wr = wid >> 1, wcn = wid & 1;
    const int xr = l15 & 7;                 // row&7 for this lane's fragment rows
    // chunked XCD swizzle: consecutive work items (sharing A panel) -> same XCD
    const int nwg = gridDim.x, orig = blockIdx.x;
    const int swz = (orig & 7) * (nwg >> 3) + (orig >> 3);
    const int bx = swz % nbx, by = swz / nbx;
    const int m0 = by * 128, n0 = bx * 128;
    const int nkt = K >> 6;

    f32x4 acc[4][4];
    const f32x4 FZ = {0.f, 0.f, 0.f, 0.f};
#pragma unroll
    for (int mi = 0; mi < 4; ++mi)
#pragma unroll
        for (int ni = 0; ni < 4; ++ni) acc[mi][ni] = FZ;

    for (int kt = 0; kt < nkt; ++kt) {
#pragma unroll
        for (int it = 0; it < 4; ++it) {
            int ci = it * 256 + tid;          // 16B chunk index, 0..1023
            int rowa = ci >> 3, sl = ci & 7;  // 8 chunks per 64-elem row
            int slx = sl ^ (rowa & 7);        // pre-swizzled global chunk
            gll16(A  + (size_t)(m0 + rowa) * K + kt * 64 + slx * 8, lds_a + ci * 8);
            gll16(BT + (size_t)(n0 + rowa) * K + kt * 64 + slx * 8, lds_b + ci * 8);
        }
        __syncthreads();
#pragma unroll
        for (int ks = 0; ks < 2; ++ks) {
            bf16x8 av[4], bv[4];
#pragma unroll
            for (int mi = 0; mi < 4; ++mi)
                av[mi] = *(const bf16x8*)&lds_a[(wr * 64 + mi * 16 + l15) * 64 +
                                                ((ks * 4 + lhi) ^ xr) * 8];
#pragma unroll
            for (int ni = 0; ni < 4; ++ni)
                bv[ni] = *(const bf16x8*)&lds_b[(wcn * 64 + ni * 16 + l15) * 64 +
                                                ((ks * 4 + lhi) ^ xr) * 8];
#pragma unroll
            for (int mi = 0; mi < 4; ++mi)
#pragma unroll
                for (int ni = 0; ni < 4; ++ni)
                    acc[mi][ni] = MFMA_(av[mi], bv[ni], acc[mi][ni]);
        }
        __syncthreads();
    }

    // ---- epilogue: wave-private LDS transpose -> coalesced stores ----
    // scratch per wave: 16 rows x 68 words = 4352 B in lds_a region
    float* sc = (float*)&lds_a[0] + (size_t)wid * 1088;
    float bs[4];
#pragma unroll
    for (int nf = 0; nf < 4; ++nf)
        bs[nf] = HAS_BIAS ? bias[n0 + wcn * 64 + nf * 16 + l15] : 0.f;

#pragma unroll
    for (int pass = 0; pass < 4; ++pass) {
        const int mf = pass;
#pragma unroll
        for (int nf = 0; nf < 4; ++nf)
#pragma unroll
            for (int r = 0; r < 4; ++r) {
                float v = acc[mf][nf][r] + bs[nf];
                if (DO_GELU) v = gelu_f(v);
                sc[(lhi * 4 + r) * 68 + nf * 16 + l15] = v;
            }
        const int rowbase = m0 + wr * 64 + pass * 16;
        if (OUT_BF16) {
#pragma unroll
            for (int itr = 0; itr < 2; ++itr) {
                const int rr = itr * 8 + (l >> 3);
                const int c0 = (l & 7) * 8;
                float4 f0 = *(float4*)&sc[rr * 68 + c0];
                float4 f1 = *(float4*)&sc[rr * 68 + c0 + 4];
                u16x8 ov;
                ov[0] = f2bf(f0.x); ov[1] = f2bf(f0.y);
                ov[2] = f2bf(f0.z); ov[3] = f2bf(f0.w);
                ov[4] = f2bf(f1.x); ov[5] = f2bf(f1.y);
                ov[6] = f2bf(f1.z); ov[7] = f2bf(f1.w);
                *(u16x8*)((u16*)outp + (size_t)(rowbase + rr) * N + n0 + wcn * 64 + c0) = ov;
            }
        } else {
#pragma unroll
            for (int itr = 0; itr < 4; ++itr) {
                const int rr = itr * 4 + lhi;
                const int c0 = l15 * 4;
                float4 f0 = *(float4*)&sc[rr * 68 + c0];
                const size_t idx = (size_t)(rowbase + rr) * N + n0 + wcn * 64 + c0;
                if (HAS_RES) {
                    float4 rv = *(const float4*)(res + idx);
                    f0.x += rv.x; f0.y += rv.y; f0.z += rv.z; f0.w += rv.w;
                }
                *(float4*)((float*)outp + idx) = f0;
            }
        }
    }
}

// ---------------------------------------------------------------------------
// Spatial attention: one block per (b,t,h). qkv bf16 [16384][2304],
// q|k|v at col 0|768|1536 (+h*64). N=256 keys, D=64. Out bf16 [16384][768].
// R12: removed per-qb __syncthreads — p_lds is wave-private ([w] slice) and
// vt_lds is read-only after the single staging barrier, so the 4 waves can
// free-run through QK^T/softmax/PV instead of lockstep phases.
// ---------------------------------------------------------------------------
__global__ __launch_bounds__(256, 2) void sattn(const u16* __restrict__ qkv,
                                                u16* __restrict__ attno) {
    __shared__ __attribute__((aligned(16))) u16 p_lds[4][16][264];
    __shared__ __attribute__((aligned(16))) u16 vt_lds[64][264];
    const int tid = threadIdx.x, l = tid & 63, w = tid >> 6;
    const int lr = l & 15, lg = l >> 4;
    const int bid = blockIdx.x;
    const int h = bid % 12;
    const size_t R0 = (size_t)(bid / 12) * 256;
    const u16* base = qkv + R0 * 2304;
    const f32x4 FZ = {0.f, 0.f, 0.f, 0.f};

    {
        const u16* vrow = base + (size_t)tid * 2304 + 1536 + h * 64;
#pragma unroll
        for (int c = 0; c < 8; ++c) {
            bf16x8 vv = *(const bf16x8*)(vrow + c * 8);
            const u16* pv = (const u16*)&vv;
#pragma unroll
            for (int e = 0; e < 8; ++e) vt_lds[c * 8 + e][tid] = pv[e];
        }
    }
    __syncthreads();   // vt_lds ready; only barrier in the kernel

    u16* attbase = attno + R0 * 768 + h * 64;
    for (int qb = 0; qb < 4; ++qb) {
        const int qrow0 = qb * 64 + w * 16;
        f32x4 acc[16];
#pragma unroll
        for (int nt = 0; nt < 16; ++nt) acc[nt] = FZ;
        const u16* qp = base + (size_t)(qrow0 + lr) * 2304 + h * 64;
#pragma unroll
        for (int ks = 0; ks < 2; ++ks) {
            bf16x8 af = *(const bf16x8*)(qp + ks * 32 + lg * 8);
#pragma unroll
            for (int nt = 0; nt < 16; ++nt) {
                const u16* kp = base + (size_t)(nt * 16 + lr) * 2304 + 768 + h * 64 + ks * 32 + lg * 8;
                bf16x8 bfr = *(const bf16x8*)kp;
                acc[nt] = __builtin_amdgcn_mfma_f32_16x16x32_bf16(af, bfr, acc[nt], 0, 0, 0);
            }
        }
#pragma unroll
        for (int r = 0; r < 4; ++r) {
            float m = acc[0][r] * 0.125f;
#pragma unroll
            for (int nt = 0; nt < 16; ++nt) { acc[nt][r] *= 0.125f; m = fmaxf(m, acc[nt][r]); }
            m = fmaxf(m, __shfl_xor(m, 1));
            m = fmaxf(m, __shfl_xor(m, 2));
            m = fmaxf(m, __shfl_xor(m, 4));
            m = fmaxf(m, __shfl_xor(m, 8));
            float ssum = 0.f;
#pragma unroll
            for (int nt = 0; nt < 16; ++nt) {
                float e = __expf(acc[nt][r] - m);
                acc[nt][r] = e; ssum += e;
            }
            ssum += __shfl_xor(ssum, 1);
            ssum += __shfl_xor(ssum, 2);
            ssum += __shfl_xor(ssum, 4);
            ssum += __shfl_xor(ssum, 8);
            float inv = 1.f / ssum;
#pragma unroll
            for (int nt = 0; nt < 16; ++nt) acc[nt][r] *= inv;
        }
#pragma unroll
        for (int nt = 0; nt < 16; ++nt)
#pragma unroll
            for (int r = 0; r < 4; ++r)
                p_lds[w][lg * 4 + r][nt * 16 + lr] = f2bf(acc[nt][r]);
        // no barrier: p_lds[w] is wave-private; within-wave write->read is
        // ordered by lgkmcnt the compiler inserts before the ds_read below.
        f32x4 oacc[4];
#pragma unroll
        for (int dt = 0; dt < 4; ++dt) oacc[dt] = FZ;
#pragma unroll
        for (int ks = 0; ks < 8; ++ks) {
            bf16x8 af = *(const bf16x8*)&p_lds[w][lr][ks * 32 + lg * 8];
#pragma unroll
            for (int dt = 0; dt < 4; ++dt) {
                bf16x8 bfr = *(const bf16x8*)&vt_lds[dt * 16 + lr][ks * 32 + lg * 8];
                oacc[dt] = __builtin_amdgcn_mfma_f32_16x16x32_bf16(af, bfr, oacc[dt], 0, 0, 0);
            }
        }
#pragma unroll
        for (int dt = 0; dt < 4; ++dt)
#pragma unroll
            for (int r = 0; r < 4; ++r)
                attbase[(size_t)(qrow0 + lg * 4 + r) * 768 + dt * 16 + lr] = f2bf(oacc[dt][r]);
    }
}

// ---------------------------------------------------------------------------
// Temporal attention (causal, T=16): one wave per (b,n,h). Vector math.
// ---------------------------------------------------------------------------
__global__ __launch_bounds__(256, 4) void tattn(const u16* __restrict__ qkv,
                                                u16* __restrict__ attno) {
    __shared__ float p_lds[4][16][17];
    const int tid = threadIdx.x, l = tid & 63, wv = tid >> 6;
    const int gw = blockIdx.x * 4 + wv;
    const int h = gw % 12;
    const int bn = gw / 12;
    const int n = bn & 255, b = bn >> 8;
    const u16* base = qkv + ((size_t)(b * 16) * 256 + n) * 2304;
    const size_t tstr = (size_t)256 * 2304;
    const int tk = l & 15, g = l >> 4;

    bf16x8 kv[8];
    const u16* kp = base + (size_t)tk * tstr + 768 + h * 64;
#pragma unroll
    for (int c = 0; c < 8; ++c) kv[c] = *(const bf16x8*)(kp + c * 8);

#pragma unroll
    for (int pass = 0; pass < 4; ++pass) {
        int tq = pass * 4 + g;
        const u16* qp = base + (size_t)tq * tstr + h * 64;
        float s = 0.f;
#pragma unroll
        for (int c = 0; c < 8; ++c) {
            bf16x8 qv = *(const bf16x8*)(qp + c * 8);
#pragma unroll
            for (int e = 0; e < 8; ++e) s += (float)qv[e] * (float)kv[c][e];
        }
        s = (tk <= tq) ? s * 0.125f : -1e30f;
        float m = s;
        m = fmaxf(m, __shfl_xor(m, 1));
        m = fmaxf(m, __shfl_xor(m, 2));
        m = fmaxf(m, __shfl_xor(m, 4));
        m = fmaxf(m, __shfl_xor(m, 8));
        float p = __expf(s - m);
        float ssum = p;
        ssum += __shfl_xor(ssum, 1);
        ssum += __shfl_xor(ssum, 2);
        ssum += __shfl_xor(ssum, 4);
        ssum += __shfl_xor(ssum, 8);
        p_lds[wv][tq][tk] = p / ssum;
    }
    __syncthreads();
    float vreg[16];
#pragma unroll
    for (int t2 = 0; t2 < 16; ++t2)
        vreg[t2] = bf2f(base[(size_t)t2 * tstr + 1536 + h * 64 + l]);
    u16* ob = attno + ((size_t)(b * 16) * 256 + n) * 768 + h * 64 + l;
#pragma unroll
    for (int tq = 0; tq < 16; ++tq) {
        float o = 0.f;
#pragma unroll
        for (int t2 = 0; t2 < 16; ++t2) o += p_lds[wv][tq][t2] * vreg[t2];
        ob[(size_t)tq * 256 * 768] = f2bf(o);
    }
}

// ---------------------------------------------------------------------------
extern "C" void kernel_launch(void* const* d_in, const int* in_sizes, int n_in,
                              void* d_out, int out_size, void* d_ws, size_t ws_size,
                              hipStream_t stream) {
    (void)in_sizes; (void)n_in; (void)out_size; (void)ws_size;
    const float* x       = (const float*)d_in[0];
    const float* ln1s_g  = (const float*)d_in[1];
    const float* ln1s_b  = (const float*)d_in[2];
    const float* ln1t_g  = (const float*)d_in[3];
    const float* ln1t_b  = (const float*)d_in[4];
    const float* ln2_g   = (const float*)d_in[5];
    const float* ln2_b   = (const float*)d_in[6];
    const float* Wqkv_s  = (const float*)d_in[7];
    const float* Wproj_s = (const float*)d_in[8];
    const float* bproj_s = (const float*)d_in[9];
    const float* Wqkv_t  = (const float*)d_in[10];
    const float* Wproj_t = (const float*)d_in[11];
    const float* bproj_t = (const float*)d_in[12];
    const float* Wfc1    = (const float*)d_in[13];
    const float* bfc1    = (const float*)d_in[14];
    const float* Wfc2    = (const float*)d_in[15];
    const float* bfc2    = (const float*)d_in[16];
    float* out = (float*)d_out;

    const int M = 16384, C = 768, HID = 3072, NQKV = 2304;

    char* p = (char*)d_ws;
    auto carve = [&](size_t bytes) {
        char* r = p;
        p += (bytes + 255) & ~(size_t)255;
        return r;
    };
    u16* wqkvT_s  = (u16*)carve((size_t)NQKV * C * 2);
    u16* wprojT_s = (u16*)carve((size_t)C * C * 2);
    u16* wqkvT_t  = (u16*)carve((size_t)NQKV * C * 2);
    u16* wprojT_t = (u16*)carve((size_t)C * C * 2);
    u16* wfc1T    = (u16*)carve((size_t)HID * C * 2);
    u16* wfc2T    = (u16*)carve((size_t)C * HID * 2);
    u16* xn       = (u16*)carve((size_t)M * C * 2);
    u16* attno    = (u16*)carve((size_t)M * C * 2);
    u16* big      = (u16*)carve((size_t)M * HID * 2);  // qkv (M x 2304) or h1 (M x 3072)

    // weight transposes (f32 [K][N] -> bf16 [N][K])
    wtrans<<<dim3(NQKV / 32, C / 32), 256, 0, stream>>>(Wqkv_s, wqkvT_s, C, NQKV);
    wtrans<<<dim3(C / 32, C / 32), 256, 0, stream>>>(Wproj_s, wprojT_s, C, C);
    wtrans<<<dim3(NQKV / 32, C / 32), 256, 0, stream>>>(Wqkv_t, wqkvT_t, C, NQKV);
    wtrans<<<dim3(C / 32, C / 32), 256, 0, stream>>>(Wproj_t, wprojT_t, C, C);
    wtrans<<<dim3(HID / 32, C / 32), 256, 0, stream>>>(Wfc1, wfc1T, C, HID);
    wtrans<<<dim3(C / 32, HID / 32), 256, 0, stream>>>(Wfc2, wfc2T, HID, C);

    // ---- spatial attention block ----
    ln_bf16<<<M / 4, 256, 0, stream>>>(x, ln1s_g, ln1s_b, xn);
    gemm128<0, 0, 0, 1><<<(NQKV / 128) * (M / 128), 256, 0, stream>>>(
        xn, wqkvT_s, nullptr, nullptr, big, M, NQKV, C, NQKV / 128);
    sattn<<<768, 256, 0, stream>>>(big, attno);
    gemm128<1, 1, 0, 0><<<(C / 128) * (M / 128), 256, 0, stream>>>(
        attno, wprojT_s, bproj_s, x, out, M, C, C, C / 128);

    // ---- temporal attention block ----
    ln_bf16<<<M / 4, 256, 0, stream>>>(out, ln1t_g, ln1t_b, xn);
    gemm128<0, 0, 0, 1><<<(NQKV / 128) * (M / 128), 256, 0, stream>>>(
        xn, wqkvT_t, nullptr, nullptr, big, M, NQKV, C, NQKV / 128);
    tattn<<<12288 / 4, 256, 0, stream>>>(big, attno);
    gemm128<1, 1, 0, 0><<<(C / 128) * (M / 128), 256, 0, stream>>>(
        attno, wprojT_t, bproj_t, out, out, M, C, C, C / 128);

    // ---- MLP block ----
    ln_bf16<<<M / 4, 256, 0, stream>>>(out, ln2_g, ln2_b, xn);
    gemm128<1, 0, 1, 1><<<(HID / 128) * (M / 128), 256, 0, stream>>>(
        xn, wfc1T, bfc1, nullptr, big, M, HID, C, HID / 128);
    gemm128<1, 1, 0, 0><<<(C / 128) * (M / 128), 256, 0, stream>>>(
        big, wfc2T, bfc2, out, out, M, C, HID, C / 128);
}

// Round 13
// 518.612 us; speedup vs baseline: 1.1194x; 1.0474x over previous
//
#include <hip/hip_runtime.h>

typedef unsigned short u16;
typedef __attribute__((ext_vector_type(8))) __bf16 bf16x8;
typedef __attribute__((ext_vector_type(4))) float f32x4;
typedef __attribute__((ext_vector_type(4))) u16 u16x4;
typedef __attribute__((ext_vector_type(8))) u16 u16x8;

#define DEVI static __device__ __forceinline__

DEVI u16 f2bf(float f) {
    unsigned u = __float_as_uint(f);
    u += 0x7fffu + ((u >> 16) & 1u);   // RNE
    return (u16)(u >> 16);
}
DEVI float bf2f(u16 b) { return __uint_as_float(((unsigned)b) << 16); }

// fast GELU: Abramowitz-Stegun 7.1.26 erf approx, |err| < 1.5e-7
DEVI float gelu_f(float v) {
    float z = fabsf(v) * 0.70710678118654752f;
    float t = 1.f / (1.f + 0.3275911f * z);
    float p = t * (0.254829592f + t * (-0.284496736f + t * (1.421413741f +
              t * (-1.453152027f + t * 1.061405429f))));
    float erfz = 1.f - p * __expf(-z * z);
    erfz = (v < 0.f) ? -erfz : erfz;
    return 0.5f * v * (1.f + erfz);
}

// async global->LDS, 16B per lane. LDS dest is wave-uniform base + lane*16.
DEVI void gll16(const void* g, void* s) {
    __builtin_amdgcn_global_load_lds((__attribute__((address_space(1))) void*)(g),
                                     (__attribute__((address_space(3))) void*)(s),
                                     16, 0, 0);
}

// ---------------------------------------------------------------------------
// Batched weight convert+transpose: 6 jobs, f32 [K][N] -> bf16 [N][K].
// ---------------------------------------------------------------------------
struct WTJob { const float* in; u16* out; int K; int N; int nbx; int start; };
struct WTJobs { WTJob j[6]; };

__global__ __launch_bounds__(256) void wtrans_all(WTJobs jobs) {
    __shared__ float tile[32][33];
    const int bid = blockIdx.x;
    int ji = 0;
#pragma unroll
    for (int i = 1; i < 6; ++i) ji = (bid >= jobs.j[i].start) ? i : ji;
    const WTJob J = jobs.j[ji];
    const int tix = bid - J.start;
    const int n0 = (tix % J.nbx) * 32, k0 = (tix / J.nbx) * 32;
    const int t = threadIdx.x;
    const int r = t >> 3, c4 = (t & 7) << 2;
    float4 v = *(const float4*)(J.in + (size_t)(k0 + r) * J.N + n0 + c4);
    tile[r][c4 + 0] = v.x; tile[r][c4 + 1] = v.y;
    tile[r][c4 + 2] = v.z; tile[r][c4 + 3] = v.w;
    __syncthreads();
    u16x4 o;
    o.x = f2bf(tile[c4 + 0][r]);
    o.y = f2bf(tile[c4 + 1][r]);
    o.z = f2bf(tile[c4 + 2][r]);
    o.w = f2bf(tile[c4 + 3][r]);
    *(u16x4*)(J.out + (size_t)(n0 + r) * J.K + k0 + c4) = o;
}

// ---------------------------------------------------------------------------
// LayerNorm, f32 input: [M][768] -> bf16 [M][768]; one wave per row.
// ---------------------------------------------------------------------------
__global__ __launch_bounds__(256) void ln_f32(const float* __restrict__ x,
                                              const float* __restrict__ g,
                                              const float* __restrict__ b,
                                              u16* __restrict__ out) {
    int l = threadIdx.x & 63;
    size_t row = (size_t)blockIdx.x * 4 + (threadIdx.x >> 6);
    const float4* xr = (const float4*)(x + row * 768);
    float4 vv[3];
    vv[0] = xr[l]; vv[1] = xr[l + 64]; vv[2] = xr[l + 128];
    float s = 0.f, ss = 0.f;
#pragma unroll
    for (int i = 0; i < 3; ++i) {
        s  += vv[i].x + vv[i].y + vv[i].z + vv[i].w;
        ss += vv[i].x * vv[i].x + vv[i].y * vv[i].y + vv[i].z * vv[i].z + vv[i].w * vv[i].w;
    }
#pragma unroll
    for (int m = 1; m < 64; m <<= 1) { s += __shfl_xor(s, m); ss += __shfl_xor(ss, m); }
    float mean = s * (1.f / 768.f);
    float rstd = rsqrtf(ss * (1.f / 768.f) - mean * mean + 1e-5f);
    const float4* gr = (const float4*)g;
    const float4* br = (const float4*)b;
    u16* orow = out + row * 768;
#pragma unroll
    for (int i = 0; i < 3; ++i) {
        float4 gv = gr[l + i * 64], bv = br[l + i * 64];
        u16x4 o;
        o.x = f2bf((vv[i].x - mean) * rstd * gv.x + bv.x);
        o.y = f2bf((vv[i].y - mean) * rstd * gv.y + bv.y);
        o.z = f2bf((vv[i].z - mean) * rstd * gv.z + bv.z);
        o.w = f2bf((vv[i].w - mean) * rstd * gv.w + bv.w);
        *(u16x4*)(orow + l * 4 + i * 256) = o;
    }
}

// ---------------------------------------------------------------------------
// LayerNorm, bf16 input: [M][768] -> bf16 [M][768]; one wave per row.
// ---------------------------------------------------------------------------
__global__ __launch_bounds__(256) void ln_b16(const u16* __restrict__ x,
                                              const float* __restrict__ g,
                                              const float* __restrict__ b,
                                              u16* __restrict__ out) {
    int l = threadIdx.x & 63;
    size_t row = (size_t)blockIdx.x * 4 + (threadIdx.x >> 6);
    const u16* xr = x + row * 768;
    float4 vv[3];
#pragma unroll
    for (int i = 0; i < 3; ++i) {
        u16x4 t = *(const u16x4*)(xr + l * 4 + i * 256);
        vv[i].x = bf2f(t.x); vv[i].y = bf2f(t.y);
        vv[i].z = bf2f(t.z); vv[i].w = bf2f(t.w);
    }
    float s = 0.f, ss = 0.f;
#pragma unroll
    for (int i = 0; i < 3; ++i) {
        s  += vv[i].x + vv[i].y + vv[i].z + vv[i].w;
        ss += vv[i].x * vv[i].x + vv[i].y * vv[i].y + vv[i].z * vv[i].z + vv[i].w * vv[i].w;
    }
#pragma unroll
    for (int m = 1; m < 64; m <<= 1) { s += __shfl_xor(s, m); ss += __shfl_xor(ss, m); }
    float mean = s * (1.f / 768.f);
    float rstd = rsqrtf(ss * (1.f / 768.f) - mean * mean + 1e-5f);
    const float4* gr = (const float4*)g;
    const float4* br = (const float4*)b;
    u16* orow = out + row * 768;
#pragma unroll
    for (int i = 0; i < 3; ++i) {
        float4 gv = gr[l + i * 64], bv = br[l + i * 64];
        u16x4 o;
        o.x = f2bf((vv[i].x - mean) * rstd * gv.x + bv.x);
        o.y = f2bf((vv[i].y - mean) * rstd * gv.y + bv.y);
        o.z = f2bf((vv[i].z - mean) * rstd * gv.z + bv.z);
        o.w = f2bf((vv[i].w - mean) * rstd * gv.w + bv.w);
        *(u16x4*)(orow + l * 4 + i * 256) = o;
    }
}

// ---------------------------------------------------------------------------
// GEMM 128x128 — R10 main loop verbatim (R1 loop + chunked XCD swizzle + XOR
// bank-swizzle both sides). R13: epilogue gains RES_BF16 + bf16-out residual.
// C[M][N] = A[M][K] (bf16) @ BT[N][K] (bf16). 4 waves (2x2), 64x64/wave.
// ---------------------------------------------------------------------------
#define MFMA_(a, b, c) __builtin_amdgcn_mfma_f32_16x16x32_bf16(a, b, c, 0, 0, 0)

template <int HAS_BIAS, int HAS_RES, int RES_BF16, int DO_GELU, int OUT_BF16>
__global__ __launch_bounds__(256, 2) void gemm128(const u16* __restrict__ A,
                                                  const u16* __restrict__ BT,
                                                  const float* __restrict__ bias,
                                                  const void* res, void* outp,
                                                  int M, int N, int K, int nbx) {
    __shared__ __attribute__((aligned(16))) u16 lds_a[128 * 64];
    __shared__ __attribute__((aligned(16))) u16 lds_b[128 * 64];
    const int tid = threadIdx.x, l = tid & 63, wid = tid >> 6;
    const int l15 = l & 15, lhi = l >> 4;
    const int wr = wid >> 1, wcn = wid & 1;
    const int xr = l15 & 7;                 // row&7 for this lane's fragment rows
    // chunked XCD swizzle: consecutive work items (sharing A panel) -> same XCD
    const int nwg = gridDim.x, orig = blockIdx.x;
    const int swz = (orig & 7) * (nwg >> 3) + (orig >> 3);
    const int bx = swz % nbx, by = swz / nbx;
    const int m0 = by * 128, n0 = bx * 128;
    const int nkt = K >> 6;

    f32x4 acc[4][4];
    const f32x4 FZ = {0.f, 0.f, 0.f, 0.f};
#pragma unroll
    for (int mi = 0; mi < 4; ++mi)
#pragma unroll
        for (int ni = 0; ni < 4; ++ni) acc[mi][ni] = FZ;

    for (int kt = 0; kt < nkt; ++kt) {
#pragma unroll
        for (int it = 0; it < 4; ++it) {
            int ci = it * 256 + tid;          // 16B chunk index, 0..1023
            int rowa = ci >> 3, sl = ci & 7;  // 8 chunks per 64-elem row
            int slx = sl ^ (rowa & 7);        // pre-swizzled global chunk
            gll16(A  + (size_t)(m0 + rowa) * K + kt * 64 + slx * 8, lds_a + ci * 8);
            gll16(BT + (size_t)(n0 + rowa) * K + kt * 64 + slx * 8, lds_b + ci * 8);
        }
        __syncthreads();
#pragma unroll
        for (int ks = 0; ks < 2; ++ks) {
            bf16x8 av[4], bv[4];
#pragma unroll
            for (int mi = 0; mi < 4; ++mi)
                av[mi] = *(const bf16x8*)&lds_a[(wr * 64 + mi * 16 + l15) * 64 +
                                                ((ks * 4 + lhi) ^ xr) * 8];
#pragma unroll
            for (int ni = 0; ni < 4; ++ni)
                bv[ni] = *(const bf16x8*)&lds_b[(wcn * 64 + ni * 16 + l15) * 64 +
                                                ((ks * 4 + lhi) ^ xr) * 8];
#pragma unroll
            for (int mi = 0; mi < 4; ++mi)
#pragma unroll
                for (int ni = 0; ni < 4; ++ni)
                    acc[mi][ni] = MFMA_(av[mi], bv[ni], acc[mi][ni]);
        }
        __syncthreads();
    }

    // ---- epilogue: wave-private LDS transpose -> coalesced stores ----
    float* sc = (float*)&lds_a[0] + (size_t)wid * 1088;   // 16 rows x 68 words
    float bs[4];
#pragma unroll
    for (int nf = 0; nf < 4; ++nf)
        bs[nf] = HAS_BIAS ? bias[n0 + wcn * 64 + nf * 16 + l15] : 0.f;

#pragma unroll
    for (int pass = 0; pass < 4; ++pass) {
        const int mf = pass;
#pragma unroll
        for (int nf = 0; nf < 4; ++nf)
#pragma unroll
            for (int r = 0; r < 4; ++r) {
                float v = acc[mf][nf][r] + bs[nf];
                if (DO_GELU) v = gelu_f(v);
                sc[(lhi * 4 + r) * 68 + nf * 16 + l15] = v;
            }
        const int rowbase = m0 + wr * 64 + pass * 16;
        if (OUT_BF16) {
#pragma unroll
            for (int itr = 0; itr < 2; ++itr) {
                const int rr = itr * 8 + (l >> 3);
                const int c0 = (l & 7) * 8;
                float4 f0 = *(float4*)&sc[rr * 68 + c0];
                float4 f1 = *(float4*)&sc[rr * 68 + c0 + 4];
                const size_t idx = (size_t)(rowbase + rr) * N + n0 + wcn * 64 + c0;
                if (HAS_RES) {
                    if (RES_BF16) {
                        u16x8 rv = *(const u16x8*)((const u16*)res + idx);
                        f0.x += bf2f(rv[0]); f0.y += bf2f(rv[1]);
                        f0.z += bf2f(rv[2]); f0.w += bf2f(rv[3]);
                        f1.x += bf2f(rv[4]); f1.y += bf2f(rv[5]);
                        f1.z += bf2f(rv[6]); f1.w += bf2f(rv[7]);
                    } else {
                        float4 r0 = *(const float4*)((const float*)res + idx);
                        float4 r1 = *(const float4*)((const float*)res + idx + 4);
                        f0.x += r0.x; f0.y += r0.y; f0.z += r0.z; f0.w += r0.w;
                        f1.x += r1.x; f1.y += r1.y; f1.z += r1.z; f1.w += r1.w;
                    }
                }
                u16x8 ov;
                ov[0] = f2bf(f0.x); ov[1] = f2bf(f0.y);
                ov[2] = f2bf(f0.z); ov[3] = f2bf(f0.w);
                ov[4] = f2bf(f1.x); ov[5] = f2bf(f1.y);
                ov[6] = f2bf(f1.z); ov[7] = f2bf(f1.w);
                *(u16x8*)((u16*)outp + idx) = ov;
            }
        } else {
#pragma unroll
            for (int itr = 0; itr < 4; ++itr) {
                const int rr = itr * 4 + lhi;
                const int c0 = l15 * 4;
                float4 f0 = *(float4*)&sc[rr * 68 + c0];
                const size_t idx = (size_t)(rowbase + rr) * N + n0 + wcn * 64 + c0;
                if (HAS_RES) {
                    if (RES_BF16) {
                        u16x4 rv = *(const u16x4*)((const u16*)res + idx);
                        f0.x += bf2f(rv.x); f0.y += bf2f(rv.y);
                        f0.z += bf2f(rv.z); f0.w += bf2f(rv.w);
                    } else {
                        float4 rv = *(const float4*)((const float*)res + idx);
                        f0.x += rv.x; f0.y += rv.y; f0.z += rv.z; f0.w += rv.w;
                    }
                }
                *(float4*)((float*)outp + idx) = f0;
            }
        }
    }
}

// ---------------------------------------------------------------------------
// Spatial attention: one block per (b,t,h). qkv bf16 [16384][2304],
// q|k|v at col 0|768|1536 (+h*64). N=256 keys, D=64. Out bf16 [16384][768].
// ---------------------------------------------------------------------------
__global__ __launch_bounds__(256, 2) void sattn(const u16* __restrict__ qkv,
                                                u16* __restrict__ attno) {
    __shared__ __attribute__((aligned(16))) u16 p_lds[4][16][264];
    __shared__ __attribute__((aligned(16))) u16 vt_lds[64][264];
    const int tid = threadIdx.x, l = tid & 63, w = tid >> 6;
    const int lr = l & 15, lg = l >> 4;
    const int bid = blockIdx.x;
    const int h = bid % 12;
    const size_t R0 = (size_t)(bid / 12) * 256;
    const u16* base = qkv + R0 * 2304;
    const f32x4 FZ = {0.f, 0.f, 0.f, 0.f};

    {
        const u16* vrow = base + (size_t)tid * 2304 + 1536 + h * 64;
#pragma unroll
        for (int c = 0; c < 8; ++c) {
            bf16x8 vv = *(const bf16x8*)(vrow + c * 8);
            const u16* pv = (const u16*)&vv;
#pragma unroll
            for (int e = 0; e < 8; ++e) vt_lds[c * 8 + e][tid] = pv[e];
        }
    }
    __syncthreads();   // vt_lds ready; only barrier in the kernel

    u16* attbase = attno + R0 * 768 + h * 64;
    for (int qb = 0; qb < 4; ++qb) {
        const int qrow0 = qb * 64 + w * 16;
        f32x4 acc[16];
#pragma unroll
        for (int nt = 0; nt < 16; ++nt) acc[nt] = FZ;
        const u16* qp = base + (size_t)(qrow0 + lr) * 2304 + h * 64;
#pragma unroll
        for (int ks = 0; ks < 2; ++ks) {
            bf16x8 af = *(const bf16x8*)(qp + ks * 32 + lg * 8);
#pragma unroll
            for (int nt = 0; nt < 16; ++nt) {
                const u16* kp = base + (size_t)(nt * 16 + lr) * 2304 + 768 + h * 64 + ks * 32 + lg * 8;
                bf16x8 bfr = *(const bf16x8*)kp;
                acc[nt] = __builtin_amdgcn_mfma_f32_16x16x32_bf16(af, bfr, acc[nt], 0, 0, 0);
            }
        }
#pragma unroll
        for (int r = 0; r < 4; ++r) {
            float m = acc[0][r] * 0.125f;
#pragma unroll
            for (int nt = 0; nt < 16; ++nt) { acc[nt][r] *= 0.125f; m = fmaxf(m, acc[nt][r]); }
            m = fmaxf(m, __shfl_xor(m, 1));
            m = fmaxf(m, __shfl_xor(m, 2));
            m = fmaxf(m, __shfl_xor(m, 4));
            m = fmaxf(m, __shfl_xor(m, 8));
            float ssum = 0.f;
#pragma unroll
            for (int nt = 0; nt < 16; ++nt) {
                float e = __expf(acc[nt][r] - m);
                acc[nt][r] = e; ssum += e;
            }
            ssum += __shfl_xor(ssum, 1);
            ssum += __shfl_xor(ssum, 2);
            ssum += __shfl_xor(ssum, 4);
            ssum += __shfl_xor(ssum, 8);
            float inv = 1.f / ssum;
#pragma unroll
            for (int nt = 0; nt < 16; ++nt) acc[nt][r] *= inv;
        }
#pragma unroll
        for (int nt = 0; nt < 16; ++nt)
#pragma unroll
            for (int r = 0; r < 4; ++r)
                p_lds[w][lg * 4 + r][nt * 16 + lr] = f2bf(acc[nt][r]);
        f32x4 oacc[4];
#pragma unroll
        for (int dt = 0; dt < 4; ++dt) oacc[dt] = FZ;
#pragma unroll
        for (int ks = 0; ks < 8; ++ks) {
            bf16x8 af = *(const bf16x8*)&p_lds[w][lr][ks * 32 + lg * 8];
#pragma unroll
            for (int dt = 0; dt < 4; ++dt) {
                bf16x8 bfr = *(const bf16x8*)&vt_lds[dt * 16 + lr][ks * 32 + lg * 8];
                oacc[dt] = __builtin_amdgcn_mfma_f32_16x16x32_bf16(af, bfr, oacc[dt], 0, 0, 0);
            }
        }
#pragma unroll
        for (int dt = 0; dt < 4; ++dt)
#pragma unroll
            for (int r = 0; r < 4; ++r)
                attbase[(size_t)(qrow0 + lg * 4 + r) * 768 + dt * 16 + lr] = f2bf(oacc[dt][r]);
    }
}

// ---------------------------------------------------------------------------
// Temporal attention (causal, T=16): one wave per (b,n,h). Vector math.
// ---------------------------------------------------------------------------
__global__ __launch_bounds__(256, 4) void tattn(const u16* __restrict__ qkv,
                                                u16* __restrict__ attno) {
    __shared__ float p_lds[4][16][17];
    const int tid = threadIdx.x, l = tid & 63, wv = tid >> 6;
    const int gw = blockIdx.x * 4 + wv;
    const int h = gw % 12;
    const int bn = gw / 12;
    const int n = bn & 255, b = bn >> 8;
    const u16* base = qkv + ((size_t)(b * 16) * 256 + n) * 2304;
    const size_t tstr = (size_t)256 * 2304;
    const int tk = l & 15, g = l >> 4;

    bf16x8 kv[8];
    const u16* kp = base + (size_t)tk * tstr + 768 + h * 64;
#pragma unroll
    for (int c = 0; c < 8; ++c) kv[c] = *(const bf16x8*)(kp + c * 8);

#pragma unroll
    for (int pass = 0; pass < 4; ++pass) {
        int tq = pass * 4 + g;
        const u16* qp = base + (size_t)tq * tstr + h * 64;
        float s = 0.f;
#pragma unroll
        for (int c = 0; c < 8; ++c) {
            bf16x8 qv = *(const bf16x8*)(qp + c * 8);
#pragma unroll
            for (int e = 0; e < 8; ++e) s += (float)qv[e] * (float)kv[c][e];
        }
        s = (tk <= tq) ? s * 0.125f : -1e30f;
        float m = s;
        m = fmaxf(m, __shfl_xor(m, 1));
        m = fmaxf(m, __shfl_xor(m, 2));
        m = fmaxf(m, __shfl_xor(m, 4));
        m = fmaxf(m, __shfl_xor(m, 8));
        float p = __expf(s - m);
        float ssum = p;
        ssum += __shfl_xor(ssum, 1);
        ssum += __shfl_xor(ssum, 2);
        ssum += __shfl_xor(ssum, 4);
        ssum += __shfl_xor(ssum, 8);
        p_lds[wv][tq][tk] = p / ssum;
    }
    __syncthreads();
    float vreg[16];
#pragma unroll
    for (int t2 = 0; t2 < 16; ++t2)
        vreg[t2] = bf2f(base[(size_t)t2 * tstr + 1536 + h * 64 + l]);
    u16* ob = attno + ((size_t)(b * 16) * 256 + n) * 768 + h * 64 + l;
#pragma unroll
    for (int tq = 0; tq < 16; ++tq) {
        float o = 0.f;
#pragma unroll
        for (int t2 = 0; t2 < 16; ++t2) o += p_lds[wv][tq][t2] * vreg[t2];
        ob[(size_t)tq * 256 * 768] = f2bf(o);
    }
}

// ---------------------------------------------------------------------------
extern "C" void kernel_launch(void* const* d_in, const int* in_sizes, int n_in,
                              void* d_out, int out_size, void* d_ws, size_t ws_size,
                              hipStream_t stream) {
    (void)in_sizes; (void)n_in; (void)out_size; (void)ws_size;
    const float* x       = (const float*)d_in[0];
    const float* ln1s_g  = (const float*)d_in[1];
    const float* ln1s_b  = (const float*)d_in[2];
    const float* ln1t_g  = (const float*)d_in[3];
    const float* ln1t_b  = (const float*)d_in[4];
    const float* ln2_g   = (const float*)d_in[5];
    const float* ln2_b   = (const float*)d_in[6];
    const float* Wqkv_s  = (const float*)d_in[7];
    const float* Wproj_s = (const float*)d_in[8];
    const float* bproj_s = (const float*)d_in[9];
    const float* Wqkv_t  = (const float*)d_in[10];
    const float* Wproj_t = (const float*)d_in[11];
    const float* bproj_t = (const float*)d_in[12];
    const float* Wfc1    = (const float*)d_in[13];
    const float* bfc1    = (const float*)d_in[14];
    const float* Wfc2    = (const float*)d_in[15];
    const float* bfc2    = (const float*)d_in[16];
    float* out = (float*)d_out;

    const int M = 16384, C = 768, HID = 3072, NQKV = 2304;

    char* p = (char*)d_ws;
    auto carve = [&](size_t bytes) {
        char* r = p;
        p += (bytes + 255) & ~(size_t)255;
        return r;
    };
    u16* wqkvT_s  = (u16*)carve((size_t)NQKV * C * 2);
    u16* wprojT_s = (u16*)carve((size_t)C * C * 2);
    u16* wqkvT_t  = (u16*)carve((size_t)NQKV * C * 2);
    u16* wprojT_t = (u16*)carve((size_t)C * C * 2);
    u16* wfc1T    = (u16*)carve((size_t)HID * C * 2);
    u16* wfc2T    = (u16*)carve((size_t)C * HID * 2);
    u16* xn       = (u16*)carve((size_t)M * C * 2);
    u16* attno    = (u16*)carve((size_t)M * C * 2);
    u16* big      = (u16*)carve((size_t)M * HID * 2);  // qkv (M x 2304) or h1 (M x 3072)
    u16* xb2      = (u16*)carve((size_t)M * C * 2);    // bf16 residual after temporal
    u16* xb1      = (u16*)d_out;  // bf16 residual after spatial; d_out is dead
                                  // until fc2 writes the final f32 output

    // batched weight transposes (f32 [K][N] -> bf16 [N][K]); 6 jobs, 1 launch
    WTJobs jobs;
    int acc = 0;
    auto setjob = [&](int i, const float* in, u16* o, int K, int N) {
        jobs.j[i] = {in, o, K, N, N / 32, acc};
        acc += (N / 32) * (K / 32);
    };
    setjob(0, Wqkv_s, wqkvT_s, C, NQKV);
    setjob(1, Wproj_s, wprojT_s, C, C);
    setjob(2, Wqkv_t, wqkvT_t, C, NQKV);
    setjob(3, Wproj_t, wprojT_t, C, C);
    setjob(4, Wfc1, wfc1T, C, HID);
    setjob(5, Wfc2, wfc2T, HID, C);
    wtrans_all<<<acc, 256, 0, stream>>>(jobs);

    // ---- spatial attention block ----
    ln_f32<<<M / 4, 256, 0, stream>>>(x, ln1s_g, ln1s_b, xn);
    gemm128<0, 0, 0, 0, 1><<<(NQKV / 128) * (M / 128), 256, 0, stream>>>(
        xn, wqkvT_s, nullptr, nullptr, big, M, NQKV, C, NQKV / 128);
    sattn<<<768, 256, 0, stream>>>(big, attno);
    gemm128<1, 1, 0, 0, 1><<<(C / 128) * (M / 128), 256, 0, stream>>>(
        attno, wprojT_s, bproj_s, x, xb1, M, C, C, C / 128);   // res f32 x -> bf16 xb1

    // ---- temporal attention block ----
    ln_b16<<<M / 4, 256, 0, stream>>>(xb1, ln1t_g, ln1t_b, xn);
    gemm128<0, 0, 0, 0, 1><<<(NQKV / 128) * (M / 128), 256, 0, stream>>>(
        xn, wqkvT_t, nullptr, nullptr, big, M, NQKV, C, NQKV / 128);
    tattn<<<12288 / 4, 256, 0, stream>>>(big, attno);
    gemm128<1, 1, 1, 0, 1><<<(C / 128) * (M / 128), 256, 0, stream>>>(
        attno, wprojT_t, bproj_t, xb1, xb2, M, C, C, C / 128); // res bf16 -> bf16 xb2

    // ---- MLP block ----
    ln_b16<<<M / 4, 256, 0, stream>>>(xb2, ln2_g, ln2_b, xn);
    gemm128<1, 0, 0, 1, 1><<<(HID / 128) * (M / 128), 256, 0, stream>>>(
        xn, wfc1T, bfc1, nullptr, big, M, HID, C, HID / 128);
    gemm128<1, 1, 1, 0, 0><<<(C / 128) * (M / 128), 256, 0, stream>>>(
        big, wfc2T, bfc2, xb2, out, M, C, HID, C / 128);       // res bf16 -> f32 out
}

// Round 14
// 517.676 us; speedup vs baseline: 1.1214x; 1.0018x over previous
//
#include <hip/hip_runtime.h>

typedef unsigned short u16;
typedef __attribute__((ext_vector_type(8))) __bf16 bf16x8;
typedef __attribute__((ext_vector_type(4))) float f32x4;
typedef __attribute__((ext_vector_type(4))) u16 u16x4;
typedef __attribute__((ext_vector_type(8))) u16 u16x8;

#define DEVI static __device__ __forceinline__

DEVI u16 f2bf(float f) {
    unsigned u = __float_as_uint(f);
    u += 0x7fffu + ((u >> 16) & 1u);   // RNE
    return (u16)(u >> 16);
}
DEVI float bf2f(u16 b) { return __uint_as_float(((unsigned)b) << 16); }

// fast GELU: Abramowitz-Stegun 7.1.26 erf approx, |err| < 1.5e-7
DEVI float gelu_f(float v) {
    float z = fabsf(v) * 0.70710678118654752f;
    float t = 1.f / (1.f + 0.3275911f * z);
    float p = t * (0.254829592f + t * (-0.284496736f + t * (1.421413741f +
              t * (-1.453152027f + t * 1.061405429f))));
    float erfz = 1.f - p * __expf(-z * z);
    erfz = (v < 0.f) ? -erfz : erfz;
    return 0.5f * v * (1.f + erfz);
}

// async global->LDS, 16B per lane. LDS dest is wave-uniform base + lane*16.
DEVI void gll16(const void* g, void* s) {
    __builtin_amdgcn_global_load_lds((__attribute__((address_space(1))) void*)(g),
                                     (__attribute__((address_space(3))) void*)(s),
                                     16, 0, 0);
}

// ---------------------------------------------------------------------------
// Batched weight convert+transpose: 6 jobs, f32 [K][N] -> bf16 [N][K].
// ---------------------------------------------------------------------------
struct WTJob { const float* in; u16* out; int K; int N; int nbx; int start; };
struct WTJobs { WTJob j[6]; };

__global__ __launch_bounds__(256) void wtrans_all(WTJobs jobs) {
    __shared__ float tile[32][33];
    const int bid = blockIdx.x;
    int ji = 0;
#pragma unroll
    for (int i = 1; i < 6; ++i) ji = (bid >= jobs.j[i].start) ? i : ji;
    const WTJob J = jobs.j[ji];
    const int tix = bid - J.start;
    const int n0 = (tix % J.nbx) * 32, k0 = (tix / J.nbx) * 32;
    const int t = threadIdx.x;
    const int r = t >> 3, c4 = (t & 7) << 2;
    float4 v = *(const float4*)(J.in + (size_t)(k0 + r) * J.N + n0 + c4);
    tile[r][c4 + 0] = v.x; tile[r][c4 + 1] = v.y;
    tile[r][c4 + 2] = v.z; tile[r][c4 + 3] = v.w;
    __syncthreads();
    u16x4 o;
    o.x = f2bf(tile[c4 + 0][r]);
    o.y = f2bf(tile[c4 + 1][r]);
    o.z = f2bf(tile[c4 + 2][r]);
    o.w = f2bf(tile[c4 + 3][r]);
    *(u16x4*)(J.out + (size_t)(n0 + r) * J.K + k0 + c4) = o;
}

// ---------------------------------------------------------------------------
// LayerNorm, f32 input: [M][768] -> bf16 [M][768]; one wave per row.
// ---------------------------------------------------------------------------
__global__ __launch_bounds__(256) void ln_f32(const float* __restrict__ x,
                                              const float* __restrict__ g,
                                              const float* __restrict__ b,
                                              u16* __restrict__ out) {
    int l = threadIdx.x & 63;
    size_t row = (size_t)blockIdx.x * 4 + (threadIdx.x >> 6);
    const float4* xr = (const float4*)(x + row * 768);
    float4 vv[3];
    vv[0] = xr[l]; vv[1] = xr[l + 64]; vv[2] = xr[l + 128];
    float s = 0.f, ss = 0.f;
#pragma unroll
    for (int i = 0; i < 3; ++i) {
        s  += vv[i].x + vv[i].y + vv[i].z + vv[i].w;
        ss += vv[i].x * vv[i].x + vv[i].y * vv[i].y + vv[i].z * vv[i].z + vv[i].w * vv[i].w;
    }
#pragma unroll
    for (int m = 1; m < 64; m <<= 1) { s += __shfl_xor(s, m); ss += __shfl_xor(ss, m); }
    float mean = s * (1.f / 768.f);
    float rstd = rsqrtf(ss * (1.f / 768.f) - mean * mean + 1e-5f);
    const float4* gr = (const float4*)g;
    const float4* br = (const float4*)b;
    u16* orow = out + row * 768;
#pragma unroll
    for (int i = 0; i < 3; ++i) {
        float4 gv = gr[l + i * 64], bv = br[l + i * 64];
        u16x4 o;
        o.x = f2bf((vv[i].x - mean) * rstd * gv.x + bv.x);
        o.y = f2bf((vv[i].y - mean) * rstd * gv.y + bv.y);
        o.z = f2bf((vv[i].z - mean) * rstd * gv.z + bv.z);
        o.w = f2bf((vv[i].w - mean) * rstd * gv.w + bv.w);
        *(u16x4*)(orow + l * 4 + i * 256) = o;
    }
}

// ---------------------------------------------------------------------------
// LayerNorm, bf16 input: [M][768] -> bf16 [M][768]; one wave per row.
// ---------------------------------------------------------------------------
__global__ __launch_bounds__(256) void ln_b16(const u16* __restrict__ x,
                                              const float* __restrict__ g,
                                              const float* __restrict__ b,
                                              u16* __restrict__ out) {
    int l = threadIdx.x & 63;
    size_t row = (size_t)blockIdx.x * 4 + (threadIdx.x >> 6);
    const u16* xr = x + row * 768;
    float4 vv[3];
#pragma unroll
    for (int i = 0; i < 3; ++i) {
        u16x4 t = *(const u16x4*)(xr + l * 4 + i * 256);
        vv[i].x = bf2f(t.x); vv[i].y = bf2f(t.y);
        vv[i].z = bf2f(t.z); vv[i].w = bf2f(t.w);
    }
    float s = 0.f, ss = 0.f;
#pragma unroll
    for (int i = 0; i < 3; ++i) {
        s  += vv[i].x + vv[i].y + vv[i].z + vv[i].w;
        ss += vv[i].x * vv[i].x + vv[i].y * vv[i].y + vv[i].z * vv[i].z + vv[i].w * vv[i].w;
    }
#pragma unroll
    for (int m = 1; m < 64; m <<= 1) { s += __shfl_xor(s, m); ss += __shfl_xor(ss, m); }
    float mean = s * (1.f / 768.f);
    float rstd = rsqrtf(ss * (1.f / 768.f) - mean * mean + 1e-5f);
    const float4* gr = (const float4*)g;
    const float4* br = (const float4*)b;
    u16* orow = out + row * 768;
#pragma unroll
    for (int i = 0; i < 3; ++i) {
        float4 gv = gr[l + i * 64], bv = br[l + i * 64];
        u16x4 o;
        o.x = f2bf((vv[i].x - mean) * rstd * gv.x + bv.x);
        o.y = f2bf((vv[i].y - mean) * rstd * gv.y + bv.y);
        o.z = f2bf((vv[i].z - mean) * rstd * gv.z + bv.z);
        o.w = f2bf((vv[i].w - mean) * rstd * gv.w + bv.w);
        *(u16x4*)(orow + l * 4 + i * 256) = o;
    }
}

// ---------------------------------------------------------------------------
// GEMM 256x128 (R14): BM=256, BN=128, BK=64, 8 waves (4M x 2N), 64x64/wave.
// Same per-wave structure/swizzles/epilogue as R10-13's 128x128; only tile
// shape + staging counts + grid change. Staged bytes/output -25%, 48 KB LDS
// -> 3 blocks/CU for cross-block epilogue overlap.
// C[M][N] = A[M][K] (bf16) @ BT[N][K] (bf16).
// ---------------------------------------------------------------------------
#define MFMA_(a, b, c) __builtin_amdgcn_mfma_f32_16x16x32_bf16(a, b, c, 0, 0, 0)

template <int HAS_BIAS, int HAS_RES, int RES_BF16, int DO_GELU, int OUT_BF16>
__global__ __launch_bounds__(512, 2) void gemm256x128(const u16* __restrict__ A,
                                                      const u16* __restrict__ BT,
                                                      const float* __restrict__ bias,
                                                      const void* res, void* outp,
                                                      int M, int N, int K, int nbx) {
    __shared__ __attribute__((aligned(16))) u16 lds_a[256 * 64];  // 32 KB
    __shared__ __attribute__((aligned(16))) u16 lds_b[128 * 64];  // 16 KB
    const int tid = threadIdx.x, l = tid & 63, wid = tid >> 6;
    const int l15 = l & 15, lhi = l >> 4;
    const int wr = wid >> 1, wcn = wid & 1;   // 4M x 2N wave grid
    const int xr = l15 & 7;                   // row&7 for fragment rows
    // chunked XCD swizzle
    const int nwg = gridDim.x, orig = blockIdx.x;
    const int swz = (orig & 7) * (nwg >> 3) + (orig >> 3);
    const int bx = swz % nbx, by = swz / nbx;
    const int m0 = by * 256, n0 = bx * 128;
    const int nkt = K >> 6;

    f32x4 acc[4][4];
    const f32x4 FZ = {0.f, 0.f, 0.f, 0.f};
#pragma unroll
    for (int mi = 0; mi < 4; ++mi)
#pragma unroll
        for (int ni = 0; ni < 4; ++ni) acc[mi][ni] = FZ;

    for (int kt = 0; kt < nkt; ++kt) {
        // stage A: 2048 chunks (256 rows x 8), 4 per thread
#pragma unroll
        for (int it = 0; it < 4; ++it) {
            int ci = it * 512 + tid;
            int rowa = ci >> 3, sl = ci & 7;
            int slx = sl ^ (rowa & 7);
            gll16(A + (size_t)(m0 + rowa) * K + kt * 64 + slx * 8, lds_a + ci * 8);
        }
        // stage B: 1024 chunks (128 rows x 8), 2 per thread
#pragma unroll
        for (int it = 0; it < 2; ++it) {
            int ci = it * 512 + tid;
            int rowb = ci >> 3, sl = ci & 7;
            int slx = sl ^ (rowb & 7);
            gll16(BT + (size_t)(n0 + rowb) * K + kt * 64 + slx * 8, lds_b + ci * 8);
        }
        __syncthreads();
#pragma unroll
        for (int ks = 0; ks < 2; ++ks) {
            bf16x8 av[4], bv[4];
#pragma unroll
            for (int mi = 0; mi < 4; ++mi)
                av[mi] = *(const bf16x8*)&lds_a[(wr * 64 + mi * 16 + l15) * 64 +
                                                ((ks * 4 + lhi) ^ xr) * 8];
#pragma unroll
            for (int ni = 0; ni < 4; ++ni)
                bv[ni] = *(const bf16x8*)&lds_b[(wcn * 64 + ni * 16 + l15) * 64 +
                                                ((ks * 4 + lhi) ^ xr) * 8];
#pragma unroll
            for (int mi = 0; mi < 4; ++mi)
#pragma unroll
                for (int ni = 0; ni < 4; ++ni)
                    acc[mi][ni] = MFMA_(av[mi], bv[ni], acc[mi][ni]);
        }
        __syncthreads();
    }

    // ---- epilogue: wave-private LDS transpose -> coalesced stores ----
    // scratch per wave: 16 rows x 68 words = 4352 B; 8 waves = 34.8 KB <= 48 KB
    float* sc = (float*)&lds_a[0] + (size_t)wid * 1088;
    float bs[4];
#pragma unroll
    for (int nf = 0; nf < 4; ++nf)
        bs[nf] = HAS_BIAS ? bias[n0 + wcn * 64 + nf * 16 + l15] : 0.f;

#pragma unroll
    for (int pass = 0; pass < 4; ++pass) {
        const int mf = pass;
#pragma unroll
        for (int nf = 0; nf < 4; ++nf)
#pragma unroll
            for (int r = 0; r < 4; ++r) {
                float v = acc[mf][nf][r] + bs[nf];
                if (DO_GELU) v = gelu_f(v);
                sc[(lhi * 4 + r) * 68 + nf * 16 + l15] = v;
            }
        const int rowbase = m0 + wr * 64 + pass * 16;
        if (OUT_BF16) {
#pragma unroll
            for (int itr = 0; itr < 2; ++itr) {
                const int rr = itr * 8 + (l >> 3);
                const int c0 = (l & 7) * 8;
                float4 f0 = *(float4*)&sc[rr * 68 + c0];
                float4 f1 = *(float4*)&sc[rr * 68 + c0 + 4];
                const size_t idx = (size_t)(rowbase + rr) * N + n0 + wcn * 64 + c0;
                if (HAS_RES) {
                    if (RES_BF16) {
                        u16x8 rv = *(const u16x8*)((const u16*)res + idx);
                        f0.x += bf2f(rv[0]); f0.y += bf2f(rv[1]);
                        f0.z += bf2f(rv[2]); f0.w += bf2f(rv[3]);
                        f1.x += bf2f(rv[4]); f1.y += bf2f(rv[5]);
                        f1.z += bf2f(rv[6]); f1.w += bf2f(rv[7]);
                    } else {
                        float4 r0 = *(const float4*)((const float*)res + idx);
                        float4 r1 = *(const float4*)((const float*)res + idx + 4);
                        f0.x += r0.x; f0.y += r0.y; f0.z += r0.z; f0.w += r0.w;
                        f1.x += r1.x; f1.y += r1.y; f1.z += r1.z; f1.w += r1.w;
                    }
                }
                u16x8 ov;
                ov[0] = f2bf(f0.x); ov[1] = f2bf(f0.y);
                ov[2] = f2bf(f0.z); ov[3] = f2bf(f0.w);
                ov[4] = f2bf(f1.x); ov[5] = f2bf(f1.y);
                ov[6] = f2bf(f1.z); ov[7] = f2bf(f1.w);
                *(u16x8*)((u16*)outp + idx) = ov;
            }
        } else {
#pragma unroll
            for (int itr = 0; itr < 4; ++itr) {
                const int rr = itr * 4 + lhi;
                const int c0 = l15 * 4;
                float4 f0 = *(float4*)&sc[rr * 68 + c0];
                const size_t idx = (size_t)(rowbase + rr) * N + n0 + wcn * 64 + c0;
                if (HAS_RES) {
                    if (RES_BF16) {
                        u16x4 rv = *(const u16x4*)((const u16*)res + idx);
                        f0.x += bf2f(rv.x); f0.y += bf2f(rv.y);
                        f0.z += bf2f(rv.z); f0.w += bf2f(rv.w);
                    } else {
                        float4 rv = *(const float4*)((const float*)res + idx);
                        f0.x += rv.x; f0.y += rv.y; f0.z += rv.z; f0.w += rv.w;
                    }
                }
                *(float4*)((float*)outp + idx) = f0;
            }
        }
    }
}

// ---------------------------------------------------------------------------
// Spatial attention: one block per (b,t,h). qkv bf16 [16384][2304],
// q|k|v at col 0|768|1536 (+h*64). N=256 keys, D=64. Out bf16 [16384][768].
// ---------------------------------------------------------------------------
__global__ __launch_bounds__(256, 2) void sattn(const u16* __restrict__ qkv,
                                                u16* __restrict__ attno) {
    __shared__ __attribute__((aligned(16))) u16 p_lds[4][16][264];
    __shared__ __attribute__((aligned(16))) u16 vt_lds[64][264];
    const int tid = threadIdx.x, l = tid & 63, w = tid >> 6;
    const int lr = l & 15, lg = l >> 4;
    const int bid = blockIdx.x;
    const int h = bid % 12;
    const size_t R0 = (size_t)(bid / 12) * 256;
    const u16* base = qkv + R0 * 2304;
    const f32x4 FZ = {0.f, 0.f, 0.f, 0.f};

    {
        const u16* vrow = base + (size_t)tid * 2304 + 1536 + h * 64;
#pragma unroll
        for (int c = 0; c < 8; ++c) {
            bf16x8 vv = *(const bf16x8*)(vrow + c * 8);
            const u16* pv = (const u16*)&vv;
#pragma unroll
            for (int e = 0; e < 8; ++e) vt_lds[c * 8 + e][tid] = pv[e];
        }
    }
    __syncthreads();   // vt_lds ready; only barrier in the kernel

    u16* attbase = attno + R0 * 768 + h * 64;
    for (int qb = 0; qb < 4; ++qb) {
        const int qrow0 = qb * 64 + w * 16;
        f32x4 acc[16];
#pragma unroll
        for (int nt = 0; nt < 16; ++nt) acc[nt] = FZ;
        const u16* qp = base + (size_t)(qrow0 + lr) * 2304 + h * 64;
#pragma unroll
        for (int ks = 0; ks < 2; ++ks) {
            bf16x8 af = *(const bf16x8*)(qp + ks * 32 + lg * 8);
#pragma unroll
            for (int nt = 0; nt < 16; ++nt) {
                const u16* kp = base + (size_t)(nt * 16 + lr) * 2304 + 768 + h * 64 + ks * 32 + lg * 8;
                bf16x8 bfr = *(const bf16x8*)kp;
                acc[nt] = __builtin_amdgcn_mfma_f32_16x16x32_bf16(af, bfr, acc[nt], 0, 0, 0);
            }
        }
#pragma unroll
        for (int r = 0; r < 4; ++r) {
            float m = acc[0][r] * 0.125f;
#pragma unroll
            for (int nt = 0; nt < 16; ++nt) { acc[nt][r] *= 0.125f; m = fmaxf(m, acc[nt][r]); }
            m = fmaxf(m, __shfl_xor(m, 1));
            m = fmaxf(m, __shfl_xor(m, 2));
            m = fmaxf(m, __shfl_xor(m, 4));
            m = fmaxf(m, __shfl_xor(m, 8));
            float ssum = 0.f;
#pragma unroll
            for (int nt = 0; nt < 16; ++nt) {
                float e = __expf(acc[nt][r] - m);
                acc[nt][r] = e; ssum += e;
            }
            ssum += __shfl_xor(ssum, 1);
            ssum += __shfl_xor(ssum, 2);
            ssum += __shfl_xor(ssum, 4);
            ssum += __shfl_xor(ssum, 8);
            float inv = 1.f / ssum;
#pragma unroll
            for (int nt = 0; nt < 16; ++nt) acc[nt][r] *= inv;
        }
#pragma unroll
        for (int nt = 0; nt < 16; ++nt)
#pragma unroll
            for (int r = 0; r < 4; ++r)
                p_lds[w][lg * 4 + r][nt * 16 + lr] = f2bf(acc[nt][r]);
        f32x4 oacc[4];
#pragma unroll
        for (int dt = 0; dt < 4; ++dt) oacc[dt] = FZ;
#pragma unroll
        for (int ks = 0; ks < 8; ++ks) {
            bf16x8 af = *(const bf16x8*)&p_lds[w][lr][ks * 32 + lg * 8];
#pragma unroll
            for (int dt = 0; dt < 4; ++dt) {
                bf16x8 bfr = *(const bf16x8*)&vt_lds[dt * 16 + lr][ks * 32 + lg * 8];
                oacc[dt] = __builtin_amdgcn_mfma_f32_16x16x32_bf16(af, bfr, oacc[dt], 0, 0, 0);
            }
        }
#pragma unroll
        for (int dt = 0; dt < 4; ++dt)
#pragma unroll
            for (int r = 0; r < 4; ++r)
                attbase[(size_t)(qrow0 + lg * 4 + r) * 768 + dt * 16 + lr] = f2bf(oacc[dt][r]);
    }
}

// ---------------------------------------------------------------------------
// Temporal attention (causal, T=16): one wave per (b,n,h). Vector math.
// ---------------------------------------------------------------------------
__global__ __launch_bounds__(256, 4) void tattn(const u16* __restrict__ qkv,
                                                u16* __restrict__ attno) {
    __shared__ float p_lds[4][16][17];
    const int tid = threadIdx.x, l = tid & 63, wv = tid >> 6;
    const int gw = blockIdx.x * 4 + wv;
    const int h = gw % 12;
    const int bn = gw / 12;
    const int n = bn & 255, b = bn >> 8;
    const u16* base = qkv + ((size_t)(b * 16) * 256 + n) * 2304;
    const size_t tstr = (size_t)256 * 2304;
    const int tk = l & 15, g = l >> 4;

    bf16x8 kv[8];
    const u16* kp = base + (size_t)tk * tstr + 768 + h * 64;
#pragma unroll
    for (int c = 0; c < 8; ++c) kv[c] = *(const bf16x8*)(kp + c * 8);

#pragma unroll
    for (int pass = 0; pass < 4; ++pass) {
        int tq = pass * 4 + g;
        const u16* qp = base + (size_t)tq * tstr + h * 64;
        float s = 0.f;
#pragma unroll
        for (int c = 0; c < 8; ++c) {
            bf16x8 qv = *(const bf16x8*)(qp + c * 8);
#pragma unroll
            for (int e = 0; e < 8; ++e) s += (float)qv[e] * (float)kv[c][e];
        }
        s = (tk <= tq) ? s * 0.125f : -1e30f;
        float m = s;
        m = fmaxf(m, __shfl_xor(m, 1));
        m = fmaxf(m, __shfl_xor(m, 2));
        m = fmaxf(m, __shfl_xor(m, 4));
        m = fmaxf(m, __shfl_xor(m, 8));
        float p = __expf(s - m);
        float ssum = p;
        ssum += __shfl_xor(ssum, 1);
        ssum += __shfl_xor(ssum, 2);
        ssum += __shfl_xor(ssum, 4);
        ssum += __shfl_xor(ssum, 8);
        p_lds[wv][tq][tk] = p / ssum;
    }
    __syncthreads();
    float vreg[16];
#pragma unroll
    for (int t2 = 0; t2 < 16; ++t2)
        vreg[t2] = bf2f(base[(size_t)t2 * tstr + 1536 + h * 64 + l]);
    u16* ob = attno + ((size_t)(b * 16) * 256 + n) * 768 + h * 64 + l;
#pragma unroll
    for (int tq = 0; tq < 16; ++tq) {
        float o = 0.f;
#pragma unroll
        for (int t2 = 0; t2 < 16; ++t2) o += p_lds[wv][tq][t2] * vreg[t2];
        ob[(size_t)tq * 256 * 768] = f2bf(o);
    }
}

// ---------------------------------------------------------------------------
extern "C" void kernel_launch(void* const* d_in, const int* in_sizes, int n_in,
                              void* d_out, int out_size, void* d_ws, size_t ws_size,
                              hipStream_t stream) {
    (void)in_sizes; (void)n_in; (void)out_size; (void)ws_size;
    const float* x       = (const float*)d_in[0];
    const float* ln1s_g  = (const float*)d_in[1];
    const float* ln1s_b  = (const float*)d_in[2];
    const float* ln1t_g  = (const float*)d_in[3];
    const float* ln1t_b  = (const float*)d_in[4];
    const float* ln2_g   = (const float*)d_in[5];
    const float* ln2_b   = (const float*)d_in[6];
    const float* Wqkv_s  = (const float*)d_in[7];
    const float* Wproj_s = (const float*)d_in[8];
    const float* bproj_s = (const float*)d_in[9];
    const float* Wqkv_t  = (const float*)d_in[10];
    const float* Wproj_t = (const float*)d_in[11];
    const float* bproj_t = (const float*)d_in[12];
    const float* Wfc1    = (const float*)d_in[13];
    const float* bfc1    = (const float*)d_in[14];
    const float* Wfc2    = (const float*)d_in[15];
    const float* bfc2    = (const float*)d_in[16];
    float* out = (float*)d_out;

    const int M = 16384, C = 768, HID = 3072, NQKV = 2304;

    char* p = (char*)d_ws;
    auto carve = [&](size_t bytes) {
        char* r = p;
        p += (bytes + 255) & ~(size_t)255;
        return r;
    };
    u16* wqkvT_s  = (u16*)carve((size_t)NQKV * C * 2);
    u16* wprojT_s = (u16*)carve((size_t)C * C * 2);
    u16* wqkvT_t  = (u16*)carve((size_t)NQKV * C * 2);
    u16* wprojT_t = (u16*)carve((size_t)C * C * 2);
    u16* wfc1T    = (u16*)carve((size_t)HID * C * 2);
    u16* wfc2T    = (u16*)carve((size_t)C * HID * 2);
    u16* xn       = (u16*)carve((size_t)M * C * 2);
    u16* attno    = (u16*)carve((size_t)M * C * 2);
    u16* big      = (u16*)carve((size_t)M * HID * 2);  // qkv (M x 2304) or h1 (M x 3072)
    u16* xb2      = (u16*)carve((size_t)M * C * 2);    // bf16 residual after temporal
    u16* xb1      = (u16*)d_out;  // bf16 residual after spatial; d_out is dead
                                  // until fc2 writes the final f32 output

    // batched weight transposes (f32 [K][N] -> bf16 [N][K]); 6 jobs, 1 launch
    WTJobs jobs;
    int acc = 0;
    auto setjob = [&](int i, const float* in, u16* o, int K, int N) {
        jobs.j[i] = {in, o, K, N, N / 32, acc};
        acc += (N / 32) * (K / 32);
    };
    setjob(0, Wqkv_s, wqkvT_s, C, NQKV);
    setjob(1, Wproj_s, wprojT_s, C, C);
    setjob(2, Wqkv_t, wqkvT_t, C, NQKV);
    setjob(3, Wproj_t, wprojT_t, C, C);
    setjob(4, Wfc1, wfc1T, C, HID);
    setjob(5, Wfc2, wfc2T, HID, C);
    wtrans_all<<<acc, 256, 0, stream>>>(jobs);

    // ---- spatial attention block ----
    ln_f32<<<M / 4, 256, 0, stream>>>(x, ln1s_g, ln1s_b, xn);
    gemm256x128<0, 0, 0, 0, 1><<<(NQKV / 128) * (M / 256), 512, 0, stream>>>(
        xn, wqkvT_s, nullptr, nullptr, big, M, NQKV, C, NQKV / 128);
    sattn<<<768, 256, 0, stream>>>(big, attno);
    gemm256x128<1, 1, 0, 0, 1><<<(C / 128) * (M / 256), 512, 0, stream>>>(
        attno, wprojT_s, bproj_s, x, xb1, M, C, C, C / 128);   // res f32 x -> bf16 xb1

    // ---- temporal attention block ----
    ln_b16<<<M / 4, 256, 0, stream>>>(xb1, ln1t_g, ln1t_b, xn);
    gemm256x128<0, 0, 0, 0, 1><<<(NQKV / 128) * (M / 256), 512, 0, stream>>>(
        xn, wqkvT_t, nullptr, nullptr, big, M, NQKV, C, NQKV / 128);
    tattn<<<12288 / 4, 256, 0, stream>>>(big, attno);
    gemm256x128<1, 1, 1, 0, 1><<<(C / 128) * (M / 256), 512, 0, stream>>>(
        attno, wprojT_t, bproj_t, xb1, xb2, M, C, C, C / 128); // res bf16 -> bf16 xb2

    // ---- MLP block ----
    ln_b16<<<M / 4, 256, 0, stream>>>(xb2, ln2_g, ln2_b, xn);
    gemm256x128<1, 0, 0, 1, 1><<<(HID / 128) * (M / 256), 512, 0, stream>>>(
        xn, wfc1T, bfc1, nullptr, big, M, HID, C, HID / 128);
    gemm256x128<1, 1, 1, 0, 0><<<(C / 128) * (M / 256), 512, 0, stream>>>(
        big, wfc2T, bfc2, xb2, out, M, C, HID, C / 128);       // res bf16 -> f32 out
}